// Round 3
// baseline (935.538 us; speedup 1.0000x reference)
//
#include <hip/hip_runtime.h>
#include <hip/hip_bf16.h>

// MSA: x[2,4096,768] f32, wq/wk/wv/wo[768,768] f32, bo[768] f32 -> out[2,4096,768] f32
// Internal compute: bf16 MFMA (16x16x32) with fp32 accumulate.
// Pipeline: (1) QKV proj GEMM -> ws (bf16), (2) flash attention -> ws (bf16),
// (3) out proj + bias -> d_out (fp32).

#define HEADS 12
#define NSEQ  4096
#define DIM   768
#define DH    64
#define BATCH 2

typedef __attribute__((ext_vector_type(8))) short bf16x8;   // MFMA A/B frag (8 bf16, 4 VGPR)
typedef __attribute__((ext_vector_type(4))) float f32x4;    // MFMA C/D frag

static __device__ __forceinline__ short f2bf(float f) {
    __hip_bfloat16 h = __float2bfloat16(f);   // RNE
    return *reinterpret_cast<short*>(&h);
}

// Load an 8-element MFMA fragment from fp32 storage, converting to bf16.
static __device__ __forceinline__ bf16x8 load_frag_f32(const float* __restrict__ base, size_t elem_off) {
    const float* p = base + elem_off;
    float4 f0 = *(const float4*)p;
    float4 f1 = *(const float4*)(p + 4);
    bf16x8 r;
    r[0] = f2bf(f0.x); r[1] = f2bf(f0.y); r[2] = f2bf(f0.z); r[3] = f2bf(f0.w);
    r[4] = f2bf(f1.x); r[5] = f2bf(f1.y); r[6] = f2bf(f1.z); r[7] = f2bf(f1.w);
    return r;
}

// ---------------------------------------------------------------------------
// Kernel 1: QKV projection. y = x @ W^T (W stored [out,in] row-major => both
// operands contiguous along k). Block tile 128x64 (4 waves x 32 rows).
// grid (8192/128, 768/64, 3). Q,K written [b,h,n,d] bf16; V transposed
// [b,h,d,n] bf16 (so the PV MFMA B-operand is contiguous along key).
// ---------------------------------------------------------------------------
__global__ __launch_bounds__(256) void qkv_proj_kernel(
    const float* __restrict__ x,  const float* __restrict__ wq,
    const float* __restrict__ wk, const float* __restrict__ wv,
    short* __restrict__ qb, short* __restrict__ kb, short* __restrict__ vtb)
{
    const int wave = threadIdx.x >> 6, lane = threadIdx.x & 63;
    const int lrow = lane & 15, lquad = lane >> 4;
    const int which = blockIdx.z;
    const float* __restrict__ W = (which == 0) ? wq : ((which == 1) ? wk : wv);

    const int m0 = blockIdx.x * 128 + wave * 32;  // this wave's 32 rows
    const int o0 = blockIdx.y * 64;               // 64 output cols

    f32x4 acc[2][4];
    for (int rb = 0; rb < 2; rb++)
        for (int ct = 0; ct < 4; ct++)
            acc[rb][ct] = (f32x4){0.f, 0.f, 0.f, 0.f};

    for (int k0 = 0; k0 < DIM; k0 += 32) {
        bf16x8 a[2], b[4];
        #pragma unroll
        for (int rb = 0; rb < 2; rb++)
            a[rb] = load_frag_f32(x, (size_t)(m0 + rb*16 + lrow) * DIM + k0 + lquad*8);
        #pragma unroll
        for (int ct = 0; ct < 4; ct++)
            b[ct] = load_frag_f32(W, (size_t)(o0 + ct*16 + lrow) * DIM + k0 + lquad*8);
        #pragma unroll
        for (int rb = 0; rb < 2; rb++)
            #pragma unroll
            for (int ct = 0; ct < 4; ct++)
                acc[rb][ct] = __builtin_amdgcn_mfma_f32_16x16x32_bf16(a[rb], b[ct], acc[rb][ct], 0, 0, 0);
    }

    // C/D layout: col = lane&15, row = (lane>>4)*4 + reg  [m89/m91 verified]
    #pragma unroll
    for (int rb = 0; rb < 2; rb++)
        #pragma unroll
        for (int ct = 0; ct < 4; ct++)
            #pragma unroll
            for (int r = 0; r < 4; r++) {
                const int m  = m0 + rb*16 + lquad*4 + r;
                const int o  = o0 + ct*16 + lrow;
                const int bb = m >> 12, n = m & (NSEQ - 1);
                const int h  = o >> 6,  dd = o & 63;
                const short v = f2bf(acc[rb][ct][r]);
                if (which == 0)      qb[(((size_t)(bb*HEADS + h) * NSEQ) + n) * DH + dd] = v;
                else if (which == 1) kb[(((size_t)(bb*HEADS + h) * NSEQ) + n) * DH + dd] = v;
                else                 vtb[((size_t)(bb*HEADS + h) * DH + dd) * NSEQ + n]  = v;
            }
}

// ---------------------------------------------------------------------------
// Kernel 2: flash attention. grid (4096/128, 12, 2), 4 waves, 32 q-rows/wave.
// Per 64-key tile: S = Q K^T / 8 via MFMA; online softmax (16-lane shfl over
// C-layout rows); P -> LDS (C-layout -> A-operand layout, m120-verified
// transform); PV MFMA vs V^T. Per-wave private LDS region (in-wave DS
// ordering + compiler lgkmcnt) => no __syncthreads.
// ---------------------------------------------------------------------------
__global__ __launch_bounds__(256) void attn_kernel(
    const short* __restrict__ qb, const short* __restrict__ kb,
    const short* __restrict__ vtb, short* __restrict__ ob)
{
    __shared__ __align__(16) short Plds[8][16][72];  // [wave*2+rb][16 q-rows][64 keys + 8 pad]

    const int wave = threadIdx.x >> 6, lane = threadIdx.x & 63;
    const int lrow = lane & 15, lquad = lane >> 4;
    const int b = blockIdx.z, h = blockIdx.y;
    const int bh = b * HEADS + h;
    const int q0 = blockIdx.x * 128 + wave * 32;

    const short* __restrict__ Q  = qb  + (size_t)bh * NSEQ * DH;
    const short* __restrict__ K  = kb  + (size_t)bh * NSEQ * DH;
    const short* __restrict__ Vt = vtb + (size_t)bh * DH * NSEQ;

    // Q fragments for this wave's 32 rows, resident for the whole kernel.
    bf16x8 aq[2][2];
    #pragma unroll
    for (int rb = 0; rb < 2; rb++)
        #pragma unroll
        for (int kk = 0; kk < 2; kk++)
            aq[rb][kk] = *(const bf16x8*)(Q + (size_t)(q0 + rb*16 + lrow) * DH + kk*32 + lquad*8);

    float mrow[2][4], lsum[2][4];
    f32x4 oacc[2][4];
    #pragma unroll
    for (int rb = 0; rb < 2; rb++)
        #pragma unroll
        for (int r = 0; r < 4; r++) { mrow[rb][r] = -INFINITY; lsum[rb][r] = 0.f; }
    #pragma unroll
    for (int rb = 0; rb < 2; rb++)
        #pragma unroll
        for (int ct = 0; ct < 4; ct++)
            oacc[rb][ct] = (f32x4){0.f, 0.f, 0.f, 0.f};

    const float LOG2E = 1.44269504f;

    for (int kt = 0; kt < NSEQ / 64; kt++) {
        const int key0 = kt * 64;

        // K-tile B-fragments (identical across waves -> L1/L2 reuse)
        bf16x8 bk[4][2];
        #pragma unroll
        for (int ct = 0; ct < 4; ct++)
            #pragma unroll
            for (int kk = 0; kk < 2; kk++)
                bk[ct][kk] = *(const bf16x8*)(K + (size_t)(key0 + ct*16 + lrow) * DH + kk*32 + lquad*8);

        #pragma unroll
        for (int rb = 0; rb < 2; rb++) {
            f32x4 s[4];
            #pragma unroll
            for (int ct = 0; ct < 4; ct++) s[ct] = (f32x4){0.f, 0.f, 0.f, 0.f};
            #pragma unroll
            for (int kk = 0; kk < 2; kk++)
                #pragma unroll
                for (int ct = 0; ct < 4; ct++)
                    s[ct] = __builtin_amdgcn_mfma_f32_16x16x32_bf16(aq[rb][kk], bk[ct][kk], s[ct], 0, 0, 0);
            #pragma unroll
            for (int ct = 0; ct < 4; ct++) s[ct] *= 0.125f;   // d^-0.5

            // Online softmax per acc row (row = lquad*4 + r; 16 lanes share a row)
            #pragma unroll
            for (int r = 0; r < 4; r++) {
                float t = fmaxf(fmaxf(s[0][r], s[1][r]), fmaxf(s[2][r], s[3][r]));
                t = fmaxf(t, __shfl_xor(t, 1));
                t = fmaxf(t, __shfl_xor(t, 2));
                t = fmaxf(t, __shfl_xor(t, 4));
                t = fmaxf(t, __shfl_xor(t, 8));
                const float mold = mrow[rb][r];
                const float mnew = fmaxf(mold, t);
                const float alpha = exp2f((mold - mnew) * LOG2E);  // 0 when mold=-inf
                mrow[rb][r] = mnew;
                float rs = 0.f;
                #pragma unroll
                for (int ct = 0; ct < 4; ct++) {
                    const float pv = exp2f((s[ct][r] - mnew) * LOG2E);
                    Plds[wave*2 + rb][lquad*4 + r][ct*16 + lrow] = f2bf(pv);
                    rs += pv;
                }
                rs += __shfl_xor(rs, 1);
                rs += __shfl_xor(rs, 2);
                rs += __shfl_xor(rs, 4);
                rs += __shfl_xor(rs, 8);
                lsum[rb][r] = lsum[rb][r] * alpha + rs;
                #pragma unroll
                for (int ct = 0; ct < 4; ct++) oacc[rb][ct][r] *= alpha;
            }
        }

        // V-tile B-fragments: B[k=key][n=d] needs contiguous key => V^T rows
        bf16x8 bv[4][2];
        #pragma unroll
        for (int ct = 0; ct < 4; ct++)
            #pragma unroll
            for (int kk = 0; kk < 2; kk++)
                bv[ct][kk] = *(const bf16x8*)(Vt + (size_t)(ct*16 + lrow) * NSEQ + key0 + kk*32 + lquad*8);

        // PV: P re-read from LDS in A-operand layout (m = lane&15, k = quad*8+j)
        #pragma unroll
        for (int rb = 0; rb < 2; rb++) {
            bf16x8 ap[2];
            #pragma unroll
            for (int kk = 0; kk < 2; kk++)
                ap[kk] = *(const bf16x8*)&Plds[wave*2 + rb][lrow][kk*32 + lquad*8];
            #pragma unroll
            for (int kk = 0; kk < 2; kk++)
                #pragma unroll
                for (int ct = 0; ct < 4; ct++)
                    oacc[rb][ct] = __builtin_amdgcn_mfma_f32_16x16x32_bf16(ap[kk], bv[ct][kk], oacc[rb][ct], 0, 0, 0);
        }
    }

    // Epilogue: O /= l, write [b, n, h*64+dd] bf16 into ws
    #pragma unroll
    for (int rb = 0; rb < 2; rb++)
        #pragma unroll
        for (int ct = 0; ct < 4; ct++)
            #pragma unroll
            for (int r = 0; r < 4; r++) {
                const int n   = q0 + rb*16 + lquad*4 + r;
                const int col = h*DH + ct*16 + lrow;
                const float v = oacc[rb][ct][r] / lsum[rb][r];
                ob[((size_t)b * NSEQ + n) * DIM + col] = f2bf(v);
            }
}

// ---------------------------------------------------------------------------
// Kernel 3: output projection. y = O @ wo^T + bo. grid (8192/128, 768/64).
// O from ws is bf16; wo/bo fp32; y fp32.
// ---------------------------------------------------------------------------
__global__ __launch_bounds__(256) void out_proj_kernel(
    const short* __restrict__ xo, const float* __restrict__ W,
    const float* __restrict__ bias, float* __restrict__ y)
{
    const int wave = threadIdx.x >> 6, lane = threadIdx.x & 63;
    const int lrow = lane & 15, lquad = lane >> 4;
    const int m0 = blockIdx.x * 128 + wave * 32;
    const int o0 = blockIdx.y * 64;

    f32x4 acc[2][4];
    for (int rb = 0; rb < 2; rb++)
        for (int ct = 0; ct < 4; ct++)
            acc[rb][ct] = (f32x4){0.f, 0.f, 0.f, 0.f};

    for (int k0 = 0; k0 < DIM; k0 += 32) {
        bf16x8 a[2], b[4];
        #pragma unroll
        for (int rb = 0; rb < 2; rb++)
            a[rb] = *(const bf16x8*)(xo + (size_t)(m0 + rb*16 + lrow) * DIM + k0 + lquad*8);
        #pragma unroll
        for (int ct = 0; ct < 4; ct++)
            b[ct] = load_frag_f32(W, (size_t)(o0 + ct*16 + lrow) * DIM + k0 + lquad*8);
        #pragma unroll
        for (int rb = 0; rb < 2; rb++)
            #pragma unroll
            for (int ct = 0; ct < 4; ct++)
                acc[rb][ct] = __builtin_amdgcn_mfma_f32_16x16x32_bf16(a[rb], b[ct], acc[rb][ct], 0, 0, 0);
    }

    #pragma unroll
    for (int rb = 0; rb < 2; rb++)
        #pragma unroll
        for (int ct = 0; ct < 4; ct++)
            #pragma unroll
            for (int r = 0; r < 4; r++) {
                const int m = m0 + rb*16 + lquad*4 + r;
                const int o = o0 + ct*16 + lrow;
                y[(size_t)m * DIM + o] = acc[rb][ct][r] + bias[o];
            }
}

extern "C" void kernel_launch(void* const* d_in, const int* in_sizes, int n_in,
                              void* d_out, int out_size, void* d_ws, size_t ws_size,
                              hipStream_t stream) {
    const float* x  = (const float*)d_in[0];
    const float* wq = (const float*)d_in[1];
    const float* wk = (const float*)d_in[2];
    const float* wv = (const float*)d_in[3];
    const float* wo = (const float*)d_in[4];
    const float* bo = (const float*)d_in[5];
    float* out = (float*)d_out;

    const size_t qkv_elems = (size_t)BATCH * HEADS * NSEQ * DH;  // 6291456
    short* qb  = (short*)d_ws;
    short* kb  = qb  + qkv_elems;
    short* vtb = kb  + qkv_elems;
    short* ob  = vtb + qkv_elems;   // [B*N, DIM] bf16; total ws use ~50.3 MB

    dim3 blk(256);
    qkv_proj_kernel<<<dim3(8192/128, DIM/64, 3), blk, 0, stream>>>(x, wq, wk, wv, qb, kb, vtb);
    attn_kernel    <<<dim3(NSEQ/128, HEADS, BATCH), blk, 0, stream>>>(qb, kb, vtb, ob);
    out_proj_kernel<<<dim3(8192/128, DIM/64, 1), blk, 0, stream>>>(ob, wo, bo, out);
}